// Round 3
// baseline (458.570 us; speedup 1.0000x reference)
//
#include <hip/hip_runtime.h>

// GCN 2-layer: h = relu(Ahat @ (x @ W) + b), twice.
// Round 11: CSR build rewritten as direct atomic build (deg -> 2-level scan ->
// atomic scatter into final col positions). Eliminates ebuf (12.8 MB rt-trip),
// the 3-pass bucketed scatter, and fill2's per-bucket LDS counting sort.
// Within-row edge order becomes arbitrary (atomic race) -- aggregate is
// order-insensitive f32 accumulation. Fused1 reverted (LDS-occupancy coupling
// slowed the scatter role: 31% occ, 80us). dinv stays in the aggregate.

#define NFEAT 128
#define BPITCH 136             // ushorts per Bs row (B-frag reads)
#define EPITCH 132             // ushorts per epilogue row: 264B -> q-groups on disjoint banks

typedef __attribute__((ext_vector_type(8))) short s8v;  // 8 bf16 MFMA A/B frag
typedef __attribute__((ext_vector_type(4))) float f4v;  // MFMA C/D frag
typedef __attribute__((ext_vector_type(2))) float f2v;  // packed f32 pair
typedef __attribute__((ext_vector_type(4))) uint u4v;   // NT-store vector

// ---- bf16 helpers (rne) ----
__device__ inline ushort f2bf(float f) {
    union { float f; uint u; } x; x.f = f;
    uint u = x.u;
    return (ushort)((u + 0x7fffu + ((u >> 16) & 1u)) >> 16);
}
__device__ inline f2v unpk(uint u) {
    union { uint u; float f; } lo, hi;
    lo.u = u << 16;
    hi.u = u & 0xffff0000u;
    return (f2v){lo.f, hi.f};
}
__device__ inline void upfma2(uint4 v, float g, f2v* a) {
    a[0] += g * unpk(v.x);
    a[1] += g * unpk(v.y);
    a[2] += g * unpk(v.z);
    a[3] += g * unpk(v.w);
}

// ---------------- CSR build: degree count (global atomics, int4 reads) --------
__global__ __launch_bounds__(256) void k_deg(const int* __restrict__ dst,
                                             int* __restrict__ deg, int E) {
    int i = blockIdx.x * 256 + threadIdx.x;
    int stride = gridDim.x * 256;
    int E4 = E >> 2;
    const int4* d4 = (const int4*)dst;
    for (int k = i; k < E4; k += stride) {
        int4 v = d4[k];
        atomicAdd(&deg[v.x], 1);
        atomicAdd(&deg[v.y], 1);
        atomicAdd(&deg[v.z], 1);
        atomicAdd(&deg[v.w], 1);
    }
    for (int k = E4 * 4 + i; k < E; k += stride) atomicAdd(&deg[dst[k]], 1);
}

// ---------------- scan level 1: per-256-node partial sums ----------------
__global__ __launch_bounds__(256) void k_scan_a(const int* __restrict__ deg,
                                                int* __restrict__ bsum, int N) {
    __shared__ int red[256];
    int t = threadIdx.x;
    int n = blockIdx.x * 256 + t;
    red[t] = (n < N) ? deg[n] : 0;
    __syncthreads();
    for (int off = 128; off >= 1; off >>= 1) {
        if (t < off) red[t] += red[t + off];
        __syncthreads();
    }
    if (t == 0) bsum[blockIdx.x] = red[0];
}

// ---------------- scan level 2: base + in-block scan -> row_ptr/wofs/dinv -----
__global__ __launch_bounds__(256) void k_scan_b(const int* __restrict__ deg,
                                                const int* __restrict__ bsum,
                                                int* __restrict__ row_ptr,
                                                int* __restrict__ wofs,
                                                float* __restrict__ dinv,
                                                int N, int E) {
    __shared__ int red[256];
    __shared__ int sc[256];
    int b = blockIdx.x, t = threadIdx.x;
    int part = 0;
    for (int j = t; j < b; j += 256) part += bsum[j];
    red[t] = part;
    __syncthreads();
    for (int off = 128; off >= 1; off >>= 1) {
        if (t < off) red[t] += red[t + off];
        __syncthreads();
    }
    int base = red[0];
    int n = b * 256 + t;
    int d = (n < N) ? deg[n] : 0;
    sc[t] = d;
    __syncthreads();
    for (int off = 1; off < 256; off <<= 1) {
        int add = (t >= off) ? sc[t - off] : 0;
        __syncthreads();
        sc[t] += add;
        __syncthreads();
    }
    if (n < N) {
        int excl = base + sc[t] - d;
        row_ptr[n] = excl;
        wofs[n] = excl;
        dinv[n] = rsqrtf((float)(d + 1));
    }
    if (n == N - 1) row_ptr[N] = E;
}

// ---------------- CSR scatter: col[atomic slot] = src ----------------
__global__ __launch_bounds__(256) void k_scat(const int* __restrict__ src,
                                              const int* __restrict__ dst,
                                              int* __restrict__ wofs,
                                              int* __restrict__ col, int E) {
    int i = blockIdx.x * 256 + threadIdx.x;
    int stride = gridDim.x * 256;
    int E4 = E >> 2;
    const int4* s4 = (const int4*)src;
    const int4* d4 = (const int4*)dst;
    for (int k = i; k < E4; k += stride) {
        int4 d = d4[k];
        int4 s = s4[k];
        col[atomicAdd(&wofs[d.x], 1)] = s.x;
        col[atomicAdd(&wofs[d.y], 1)] = s.y;
        col[atomicAdd(&wofs[d.z], 1)] = s.z;
        col[atomicAdd(&wofs[d.w], 1)] = s.w;
    }
    for (int k = E4 * 4 + i; k < E; k += stride) {
        int p = atomicAdd(&wofs[dst[k]], 1);
        col[p] = src[k];
    }
}

// ---------------- MFMA GEMM: hs[m][n] = bf16( sum_k A[m][k] W[k][n] ) ----------
// Per block: stage W -> Bs[n][k] bf16 in LDS (one barrier), 4 waves x 32 rows,
// A-frags from global, B-frags from LDS; epilogue reuses Bs (second barrier):
// per-wave region pitch 264B -> ds_write_b16 2-way max, then uint2-pair reads
// and coalesced global dwordx4 stores.
template <bool ABF16>
__global__ __launch_bounds__(256) void k_gemm3(const void* __restrict__ Ap,
                                               const float* __restrict__ W,
                                               ushort* __restrict__ hs, int M) {
    __shared__ __align__(16) ushort Bs[128 * BPITCH];  // 34816 B
    int t = threadIdx.x;

    // stage W (row-major [k][n] fp32) -> Bs[n][k] bf16
#pragma unroll
    for (int i = 0; i < 16; i++) {
        int idx = t + i * 256;   // 0..4095
        int k4 = idx >> 7;       // k = 4*k4
        int n = idx & 127;
        ushort o[4];
#pragma unroll
        for (int j = 0; j < 4; j++) o[j] = f2bf(W[(k4 * 4 + j) * NFEAT + n]);
        uint2 pk;
        __builtin_memcpy(&pk, o, 8);
        *(uint2*)&Bs[n * BPITCH + k4 * 4] = pk;
    }
    __syncthreads();

    int w = t >> 6, l = t & 63;
    int q = l >> 4, ln = l & 15;
    int wid = blockIdx.x * 4 + w;
    int row0 = wid * 32;
    bool alive = row0 < M;
    if (!alive) row0 = (M - 32) & ~31;  // clamp; stores skipped

    // ---- A fragments straight from global
    s8v afr[2][4];
#pragma unroll
    for (int mt = 0; mt < 2; mt++) {
        int row = row0 + mt * 16 + ln;
        if (row >= M) row = M - 1;
        if (ABF16) {
            const ushort* A = (const ushort*)Ap + (size_t)row * NFEAT + q * 8;
#pragma unroll
            for (int ks = 0; ks < 4; ks++)
                afr[mt][ks] = *(const s8v*)(A + ks * 32);
        } else {
            const float* A = (const float*)Ap + (size_t)row * NFEAT + q * 8;
#pragma unroll
            for (int ks = 0; ks < 4; ks++) {
                float4 f0 = *(const float4*)(A + ks * 32);
                float4 f1 = *(const float4*)(A + ks * 32 + 4);
                ushort o[8] = {f2bf(f0.x), f2bf(f0.y), f2bf(f0.z), f2bf(f0.w),
                               f2bf(f1.x), f2bf(f1.y), f2bf(f1.z), f2bf(f1.w)};
                __builtin_memcpy(&afr[mt][ks], o, 16);
            }
        }
    }

    // ---- MFMA: B-frags from LDS
    f4v acc[2][8];
#pragma unroll
    for (int mt = 0; mt < 2; mt++)
#pragma unroll
        for (int nt = 0; nt < 8; nt++) acc[mt][nt] = (f4v){0.f, 0.f, 0.f, 0.f};
#pragma unroll
    for (int nt = 0; nt < 8; nt++) {
        const ushort* Bp = Bs + (nt * 16 + ln) * BPITCH + q * 8;
#pragma unroll
        for (int ks = 0; ks < 4; ks++) {
            s8v bfr = *(const s8v*)(Bp + ks * 32);
            acc[0][nt] = __builtin_amdgcn_mfma_f32_16x16x32_bf16(afr[0][ks], bfr, acc[0][nt], 0, 0, 0);
            acc[1][nt] = __builtin_amdgcn_mfma_f32_16x16x32_bf16(afr[1][ks], bfr, acc[1][nt], 0, 0, 0);
        }
    }
    __syncthreads();  // all waves done reading Bs

    // ---- epilogue: bf16 via per-wave LDS region (pitch 264 B)
    ushort* ow = Bs + w * 32 * EPITCH;  // 8448 B per wave
#pragma unroll
    for (int mt = 0; mt < 2; mt++) {
#pragma unroll
        for (int r = 0; r < 4; r++) {
            int lrow = mt * 16 + q * 4 + r;
#pragma unroll
            for (int nt = 0; nt < 8; nt++)
                ow[lrow * EPITCH + nt * 16 + ln] = f2bf(acc[mt][nt][r]);
        }
    }
    __builtin_amdgcn_s_waitcnt(0);  // own-wave LDS writes visible
#pragma unroll
    for (int i = 0; i < 8; i++) {
        int idx = l + i * 64;  // 32 rows x 16 chunks
        int r = idx >> 4, c = idx & 15;
        const ushort* p = ow + r * EPITCH + c * 8;
        uint2 lo = *(const uint2*)p;
        uint2 hi = *(const uint2*)(p + 4);
        uint4 v = make_uint4(lo.x, lo.y, hi.x, hi.y);
        if (alive) *(uint4*)(hs + (size_t)(row0 + r) * NFEAT + c * 8) = v;
    }
}

// ---------------- Aggregation: 16-lane group per node, 2-stage pipelined gathers ----
// out[n] = relu( dinv[n] * ( dinv[n]*h[n] + sum_e dinv[col_e]*h[col_e] ) + b ).
// dinv[col] rides the same pipeline stage as the gathered row (the one-ahead
// col prefetch values are never dereferenced -> safe on workspace over-read).
template <bool OUT_BF16>
__global__ __launch_bounds__(256) void k_aggregate(const uint4* __restrict__ hs4,
                                                   const int* __restrict__ row_ptr,
                                                   const int* __restrict__ col,
                                                   const float* __restrict__ dinv,
                                                   const float* __restrict__ bias,
                                                   void* __restrict__ outp, int N) {
    int node = blockIdx.x * 16 + (threadIdx.x >> 4);
    if (node >= N) return;
    int sub = threadIdx.x & 15;

    uint4 vself = hs4[(size_t)node * 16 + sub];  // issue early, consume late
    float dself = dinv[node];
    int s = row_ptr[node], e = row_ptr[node + 1];
    int nb = (e - s) >> 2;

    f2v a[4];
#pragma unroll
    for (int j = 0; j < 4; j++) a[j] = (f2v){0.f, 0.f};

    int k = s;
    if (nb > 0) {
        // batch 0 cols + gathers + dinvs
        int c0 = col[k], c1 = col[k + 1], c2 = col[k + 2], c3 = col[k + 3];
        uint4 v0 = hs4[(size_t)c0 * 16 + sub];
        uint4 v1 = hs4[(size_t)c1 * 16 + sub];
        uint4 v2 = hs4[(size_t)c2 * 16 + sub];
        uint4 v3 = hs4[(size_t)c3 * 16 + sub];
        float g0 = dinv[c0], g1 = dinv[c1], g2 = dinv[c2], g3 = dinv[c3];
        // batch 1 cols prefetch (may over-read past e: safe workspace, never deref'd)
        int d0 = col[k + 4], d1 = col[k + 5], d2 = col[k + 6], d3 = col[k + 7];
        k += 8;
        upfma2(vself, dself, a);  // self-loop added FIRST
        for (int it = 1; it < nb; ++it, k += 4) {
            uint4 w0 = hs4[(size_t)d0 * 16 + sub];
            uint4 w1 = hs4[(size_t)d1 * 16 + sub];
            uint4 w2 = hs4[(size_t)d2 * 16 + sub];
            uint4 w3 = hs4[(size_t)d3 * 16 + sub];
            float h0 = dinv[d0], h1 = dinv[d1], h2 = dinv[d2], h3 = dinv[d3];
            int t0 = col[k], t1 = col[k + 1], t2 = col[k + 2], t3 = col[k + 3];
            upfma2(v0, g0, a); upfma2(v1, g1, a); upfma2(v2, g2, a); upfma2(v3, g3, a);
            v0 = w0; v1 = w1; v2 = w2; v3 = w3;
            g0 = h0; g1 = h1; g2 = h2; g3 = h3;
            d0 = t0; d1 = t1; d2 = t2; d3 = t3;
        }
        upfma2(v0, g0, a); upfma2(v1, g1, a); upfma2(v2, g2, a); upfma2(v3, g3, a);
        k = s + nb * 4;  // rewind prefetch overshoot for the tail
    } else {
        upfma2(vself, dself, a);
    }
    for (; k < e; ++k) {
        int c = col[k];
        upfma2(hs4[(size_t)c * 16 + sub], dinv[c], a);
    }

    float di = dinv[node];
    const float4* b4 = (const float4*)bias;
    float4 b0 = b4[sub * 2], b1 = b4[sub * 2 + 1];
    float r[8];
    r[0] = fmaxf(fmaf(di, a[0].x, b0.x), 0.f);
    r[1] = fmaxf(fmaf(di, a[0].y, b0.y), 0.f);
    r[2] = fmaxf(fmaf(di, a[1].x, b0.z), 0.f);
    r[3] = fmaxf(fmaf(di, a[1].y, b0.w), 0.f);
    r[4] = fmaxf(fmaf(di, a[2].x, b1.x), 0.f);
    r[5] = fmaxf(fmaf(di, a[2].y, b1.y), 0.f);
    r[6] = fmaxf(fmaf(di, a[3].x, b1.z), 0.f);
    r[7] = fmaxf(fmaf(di, a[3].y, b1.w), 0.f);
    if (OUT_BF16) {
        ushort o[8];
#pragma unroll
        for (int j = 0; j < 8; j++) o[j] = f2bf(r[j]);
        u4v pk;
        __builtin_memcpy(&pk, o, 16);
        __builtin_nontemporal_store(pk, (u4v*)outp + (size_t)node * 16 + sub);
    } else {
        float* orow = (float*)outp + (size_t)node * NFEAT + sub * 8;
        f4v r0 = {r[0], r[1], r[2], r[3]};
        f4v r1 = {r[4], r[5], r[6], r[7]};
        __builtin_nontemporal_store(r0, (f4v*)orow);
        __builtin_nontemporal_store(r1, (f4v*)(orow + 4));
    }
}

// ---------------- launch ----------------
extern "C" void kernel_launch(void* const* d_in, const int* in_sizes, int n_in,
                              void* d_out, int out_size, void* d_ws, size_t ws_size,
                              hipStream_t stream) {
    const float* x = (const float*)d_in[0];
    const int* ei = (const int*)d_in[1];
    const float* W1 = (const float*)d_in[2];
    const float* b1 = (const float*)d_in[3];
    const float* W2 = (const float*)d_in[4];
    const float* b2 = (const float*)d_in[5];
    float* out = (float*)d_out;

    const int N = in_sizes[0] / NFEAT;  // 100000
    const int E = in_sizes[1] / 2;      // 1600000
    const int* src = ei;
    const int* dst = ei + E;
    const int NSB = (N + 255) / 256;    // 391 scan blocks

    char* w = (char*)d_ws;
    size_t off = 0;
    auto alloc = [&](size_t bytes) -> void* {
        void* p = w + off;
        off = (off + bytes + 511) & ~(size_t)511;
        return p;
    };
    ushort* hs = (ushort*)alloc((size_t)N * NFEAT * 2);
    ushort* y1 = (ushort*)alloc((size_t)N * NFEAT * 2);
    int* row_ptr = (int*)alloc((size_t)(N + 1) * 4);
    int* col = (int*)alloc((size_t)(E + 64) * 4);   // +64: agg prefetch over-read pad
    float* dinv = (float*)alloc((size_t)N * 4);
    int* deg = (int*)alloc((size_t)N * 4);
    int* wofs = (int*)alloc((size_t)N * 4);
    int* bsum = (int*)alloc((size_t)NSB * 4);
    (void)ws_size; (void)n_in; (void)out_size;

    const int gemmBlk = (N + 127) / 128;  // 4 waves x 32 rows per block
    const int aggBlk = (N + 15) / 16;     // 16 nodes per block
    const int edgeBlk = 1536;             // grid-stride over edges (6 blocks/CU)

    hipMemsetAsync(deg, 0, (size_t)N * 4, stream);
    k_deg<<<edgeBlk, 256, 0, stream>>>(dst, deg, E);
    k_scan_a<<<NSB, 256, 0, stream>>>(deg, bsum, N);
    k_scan_b<<<NSB, 256, 0, stream>>>(deg, bsum, row_ptr, wofs, dinv, N, E);
    k_scat<<<edgeBlk, 256, 0, stream>>>(src, dst, wofs, col, E);

    k_gemm3<false><<<gemmBlk, 256, 0, stream>>>(x, W1, hs, N);
    k_aggregate<true><<<aggBlk, 256, 0, stream>>>((const uint4*)hs, row_ptr, col, dinv, b1, y1, N);
    k_gemm3<true><<<gemmBlk, 256, 0, stream>>>(y1, W2, hs, N);
    k_aggregate<false><<<aggBlk, 256, 0, stream>>>((const uint4*)hs, row_ptr, col, dinv, b2, out, N);
}

// Round 4
// 306.111 us; speedup vs baseline: 1.4981x; 1.4981x over previous
//
#include <hip/hip_runtime.h>

// GCN 2-layer: h = relu(Ahat @ (x @ W) + b), twice.
// Round 12: revert to R0 bucketed CSR build (direct atomic build lost 150us to
// 64B write amplification + atomic->store dependency). Retry build||gemm1
// fusion with the occupancy coupling FIXED: gemm restructured to 16-row waves
// (acc 32 AGPR + afr 16 VGPR) and half-K W staging (18.4 KB LDS, bank-stride
// pattern identical to proven BPITCH=136), direct short-store epilogue ->
// ~6 blocks/CU for BOTH roles (R2 was 4). Roles interleaved 1:2 by blockIdx%3.
// dinv applied in aggregate (R2 form) so gemm1 needs nothing from fill2.

#define NFEAT 128
#define BSH 7                  // 128 nodes per bucket
#define MAXNB 1024             // >= NB = ceil(N/128) = 782
#define BCAP 4096              // per-bucket ebuf capacity (mean 2046, sigma 45)
#define HP 72                  // ushorts per Bs row (64 k + 8 pad); word-stride 36 == 4 mod 32

typedef __attribute__((ext_vector_type(8))) short s8v;  // 8 bf16 MFMA A/B frag
typedef __attribute__((ext_vector_type(4))) float f4v;  // MFMA C/D frag
typedef __attribute__((ext_vector_type(2))) float f2v;  // packed f32 pair
typedef __attribute__((ext_vector_type(4))) uint u4v;   // NT-store vector

// ---- bf16 helpers (rne) ----
__device__ inline ushort f2bf(float f) {
    union { float f; uint u; } x; x.f = f;
    uint u = x.u;
    return (ushort)((u + 0x7fffu + ((u >> 16) & 1u)) >> 16);
}
__device__ inline f2v unpk(uint u) {
    union { uint u; float f; } lo, hi;
    lo.u = u << 16;
    hi.u = u & 0xffff0000u;
    return (f2v){lo.f, hi.f};
}
__device__ inline void upfma2(uint4 v, float g, f2v* a) {
    a[0] += g * unpk(v.x);
    a[1] += g * unpk(v.y);
    a[2] += g * unpk(v.z);
    a[3] += g * unpk(v.w);
}

// ---------------- GEMM body: hs[m][n] = bf16( sum_k A[m][k] W[k][n] ) ----------
// 4 waves x 16 rows per block (64 rows). W staged in two 64-k halves into an
// 18.4 KB LDS buffer; A-frags (all 4 k-slices) loaded from global up front.
// Epilogue: direct global short stores (32B runs per (r,nt); L2 write-combines).
template <bool ABF16>
__device__ inline void gemm_body(ushort* Bs, int bid, const void* __restrict__ Ap,
                                 const float* __restrict__ W,
                                 ushort* __restrict__ hs, int M) {
    int t = threadIdx.x;
    int w = t >> 6, l = t & 63;
    int q = l >> 4, ln = l & 15;
    int row0 = (bid * 4 + w) * 16;

    // ---- A fragments straight from global (k-slices 0..3, 32 k each)
    int arow = row0 + ln;
    if (arow >= M) arow = M - 1;
    s8v afr[4];
    if (ABF16) {
        const ushort* A = (const ushort*)Ap + (size_t)arow * NFEAT + q * 8;
#pragma unroll
        for (int g = 0; g < 4; g++) afr[g] = *(const s8v*)(A + g * 32);
    } else {
        const float* A = (const float*)Ap + (size_t)arow * NFEAT + q * 8;
#pragma unroll
        for (int g = 0; g < 4; g++) {
            float4 f0 = *(const float4*)(A + g * 32);
            float4 f1 = *(const float4*)(A + g * 32 + 4);
            ushort o[8] = {f2bf(f0.x), f2bf(f0.y), f2bf(f0.z), f2bf(f0.w),
                           f2bf(f1.x), f2bf(f1.y), f2bf(f1.z), f2bf(f1.w)};
            __builtin_memcpy(&afr[g], o, 16);
        }
    }

    f4v acc[8];
#pragma unroll
    for (int nt = 0; nt < 8; nt++) acc[nt] = (f4v){0.f, 0.f, 0.f, 0.f};

#pragma unroll
    for (int h = 0; h < 2; h++) {
        if (h) __syncthreads();  // all waves done reading half 0
        // stage W half h: Bs[n][kk] = bf16(W[h*64+kk][n]), kk 0..63
#pragma unroll
        for (int i = 0; i < 8; i++) {
            int idx = t + i * 256;   // 0..2047
            int k4 = idx >> 7;       // 0..15
            int n = idx & 127;
            ushort o[4];
#pragma unroll
            for (int j = 0; j < 4; j++) o[j] = f2bf(W[(h * 64 + k4 * 4 + j) * NFEAT + n]);
            uint2 pk;
            __builtin_memcpy(&pk, o, 8);
            *(uint2*)&Bs[n * HP + k4 * 4] = pk;
        }
        __syncthreads();
        // MFMA over this half: 8 nt tiles x 2 k-slices
#pragma unroll
        for (int nt = 0; nt < 8; nt++) {
            const ushort* Bp = Bs + (nt * 16 + ln) * HP + q * 8;
#pragma unroll
            for (int ks = 0; ks < 2; ks++) {
                s8v bfr = *(const s8v*)(Bp + ks * 32);
                acc[nt] = __builtin_amdgcn_mfma_f32_16x16x32_bf16(afr[h * 2 + ks], bfr, acc[nt], 0, 0, 0);
            }
        }
    }

    // ---- epilogue: direct stores, row = row0 + q*4 + r, col = nt*16 + ln
#pragma unroll
    for (int r = 0; r < 4; r++) {
        int row = row0 + q * 4 + r;
        if (row < M) {
            ushort* hp = hs + (size_t)row * NFEAT + ln;
#pragma unroll
            for (int nt = 0; nt < 8; nt++) hp[nt * 16] = f2bf(acc[nt][r]);
        }
    }
}

// ---------------- fused: bucketed edge scatter (1/3 of blocks) + gemm1 (2/3) ---
__global__ __launch_bounds__(256) void k_fused1(const int* __restrict__ src,
                                                const int* __restrict__ dst,
                                                int* __restrict__ gcnt,
                                                uint* __restrict__ ebuf,
                                                int E, int NB, int CH, int chBlk,
                                                const float* __restrict__ x,
                                                const float* __restrict__ W1,
                                                ushort* __restrict__ hs, int M) {
    __shared__ __align__(16) ushort smem[128 * HP];  // 18432 B (scatter uses 4 KB)
    int bid = blockIdx.x;
    int sid = bid / 3, r = bid % 3;
    if (r == 0 && sid < chBlk) {
        int* h = (int*)smem;
        int t = threadIdx.x;
        for (int i = t; i < NB; i += 256) h[i] = 0;
        __syncthreads();
        int e0 = sid * CH;
        int e1 = min(e0 + CH, E);
        for (int e = e0 + t; e < e1; e += 256) atomicAdd(&h[dst[e] >> BSH], 1);
        __syncthreads();
        for (int i = t; i < NB; i += 256) {
            int c = h[i];
            h[i] = c ? (i * BCAP + atomicAdd(&gcnt[i], c)) : 0;
        }
        __syncthreads();
        for (int e = e0 + t; e < e1; e += 256) {
            int d = dst[e];
            int b = d >> BSH;
            int p = atomicAdd(&h[b], 1);
            if (p < (b + 1) * BCAP)
                ebuf[p] = ((uint)src[e] << BSH) | (uint)(d & ((1 << BSH) - 1));  // N < 2^17
        }
    } else {
        int scats_before = min(sid + (r ? 1 : 0), chBlk);
        gemm_body<false>(smem, bid - scats_before, x, W1, hs, M);
    }
}

// ---------------- standalone GEMM (layer 2) ----------------
template <bool ABF16>
__global__ __launch_bounds__(256) void k_gemm3(const void* __restrict__ Ap,
                                               const float* __restrict__ W,
                                               ushort* __restrict__ hs, int M) {
    __shared__ __align__(16) ushort Bs[128 * HP];
    gemm_body<ABF16>(Bs, blockIdx.x, Ap, W, hs, M);
}

// ---------------- per-bucket CSR finalize (base scan in-block) ----------------
__global__ __launch_bounds__(256) void k_fill2(const uint* __restrict__ ebuf,
                                               const int* __restrict__ gcnt,
                                               int* __restrict__ row_ptr,
                                               float* __restrict__ dinv,
                                               int* __restrict__ col,
                                               int N, int E, int NB) {
    __shared__ int cnt[128];
    __shared__ int pre[128];
    __shared__ int sred[256];
    __shared__ int colL[BCAP];
    int b = blockIdx.x;
    int t = threadIdx.x;
    int part = 0;
    for (int j = t; j < b; j += 256) part += gcnt[j];
    sred[t] = part;
    __syncthreads();
    for (int off = 128; off >= 1; off >>= 1) {
        if (t < off) sred[t] += sred[t + off];
        __syncthreads();
    }
    int gb = sred[0];
    int m = min(gcnt[b], BCAP);
    if (t < 128) cnt[t] = 0;
    __syncthreads();
    const uint* eb = ebuf + (size_t)b * BCAP;
    for (int i = t; i < m; i += 256) atomicAdd(&cnt[eb[i] & 127], 1);
    __syncthreads();
    if (t < 128) pre[t] = cnt[t];
    __syncthreads();
    for (int off = 1; off < 128; off <<= 1) {
        int add = (t >= off && t < 128) ? pre[t - off] : 0;
        __syncthreads();
        if (t < 128) pre[t] += add;
        __syncthreads();
    }
    if (t < 128) {
        pre[t] -= cnt[t];
        int node = (b << BSH) + t;
        if (node < N) {
            row_ptr[node] = gb + pre[t];
            dinv[node] = rsqrtf((float)(cnt[t] + 1));
        }
    }
    __syncthreads();
    for (int i = t; i < m; i += 256) {
        uint p = eb[i];
        int pos = atomicAdd(&pre[p & 127], 1);
        colL[pos] = (int)(p >> BSH);
    }
    __syncthreads();
    for (int i = t; i < m; i += 256) col[gb + i] = colL[i];  // coalesced
    if (b == NB - 1 && t == 0) row_ptr[N] = E;
}

// ---------------- Aggregation: 16-lane group per node, 2-stage pipelined gathers ----
// out[n] = relu( dinv[n] * ( dinv[n]*h[n] + sum_e dinv[col_e]*h[col_e] ) + b ).
// dinv[col] rides the same pipeline stage as the gathered row (the one-ahead
// col prefetch values are never dereferenced -> safe on workspace over-read).
template <bool OUT_BF16>
__global__ __launch_bounds__(256) void k_aggregate(const uint4* __restrict__ hs4,
                                                   const int* __restrict__ row_ptr,
                                                   const int* __restrict__ col,
                                                   const float* __restrict__ dinv,
                                                   const float* __restrict__ bias,
                                                   void* __restrict__ outp, int N) {
    int node = blockIdx.x * 16 + (threadIdx.x >> 4);
    if (node >= N) return;
    int sub = threadIdx.x & 15;

    uint4 vself = hs4[(size_t)node * 16 + sub];  // issue early, consume late
    float dself = dinv[node];
    int s = row_ptr[node], e = row_ptr[node + 1];
    int nb = (e - s) >> 2;

    f2v a[4];
#pragma unroll
    for (int j = 0; j < 4; j++) a[j] = (f2v){0.f, 0.f};

    int k = s;
    if (nb > 0) {
        // batch 0 cols + gathers + dinvs
        int c0 = col[k], c1 = col[k + 1], c2 = col[k + 2], c3 = col[k + 3];
        uint4 v0 = hs4[(size_t)c0 * 16 + sub];
        uint4 v1 = hs4[(size_t)c1 * 16 + sub];
        uint4 v2 = hs4[(size_t)c2 * 16 + sub];
        uint4 v3 = hs4[(size_t)c3 * 16 + sub];
        float g0 = dinv[c0], g1 = dinv[c1], g2 = dinv[c2], g3 = dinv[c3];
        // batch 1 cols prefetch (may over-read past e: padded workspace, never deref'd)
        int d0 = col[k + 4], d1 = col[k + 5], d2 = col[k + 6], d3 = col[k + 7];
        k += 8;
        upfma2(vself, dself, a);  // self-loop added FIRST
        for (int it = 1; it < nb; ++it, k += 4) {
            uint4 w0 = hs4[(size_t)d0 * 16 + sub];
            uint4 w1 = hs4[(size_t)d1 * 16 + sub];
            uint4 w2 = hs4[(size_t)d2 * 16 + sub];
            uint4 w3 = hs4[(size_t)d3 * 16 + sub];
            float h0 = dinv[d0], h1 = dinv[d1], h2 = dinv[d2], h3 = dinv[d3];
            int t0 = col[k], t1 = col[k + 1], t2 = col[k + 2], t3 = col[k + 3];
            upfma2(v0, g0, a); upfma2(v1, g1, a); upfma2(v2, g2, a); upfma2(v3, g3, a);
            v0 = w0; v1 = w1; v2 = w2; v3 = w3;
            g0 = h0; g1 = h1; g2 = h2; g3 = h3;
            d0 = t0; d1 = t1; d2 = t2; d3 = t3;
        }
        upfma2(v0, g0, a); upfma2(v1, g1, a); upfma2(v2, g2, a); upfma2(v3, g3, a);
        k = s + nb * 4;  // rewind prefetch overshoot for the tail
    } else {
        upfma2(vself, dself, a);
    }
    for (; k < e; ++k) {
        int c = col[k];
        upfma2(hs4[(size_t)c * 16 + sub], dinv[c], a);
    }

    float di = dinv[node];
    const float4* b4 = (const float4*)bias;
    float4 b0 = b4[sub * 2], b1 = b4[sub * 2 + 1];
    float r[8];
    r[0] = fmaxf(fmaf(di, a[0].x, b0.x), 0.f);
    r[1] = fmaxf(fmaf(di, a[0].y, b0.y), 0.f);
    r[2] = fmaxf(fmaf(di, a[1].x, b0.z), 0.f);
    r[3] = fmaxf(fmaf(di, a[1].y, b0.w), 0.f);
    r[4] = fmaxf(fmaf(di, a[2].x, b1.x), 0.f);
    r[5] = fmaxf(fmaf(di, a[2].y, b1.y), 0.f);
    r[6] = fmaxf(fmaf(di, a[3].x, b1.z), 0.f);
    r[7] = fmaxf(fmaf(di, a[3].y, b1.w), 0.f);
    if (OUT_BF16) {
        ushort o[8];
#pragma unroll
        for (int j = 0; j < 8; j++) o[j] = f2bf(r[j]);
        u4v pk;
        __builtin_memcpy(&pk, o, 16);
        __builtin_nontemporal_store(pk, (u4v*)outp + (size_t)node * 16 + sub);
    } else {
        float* orow = (float*)outp + (size_t)node * NFEAT + sub * 8;
        f4v r0 = {r[0], r[1], r[2], r[3]};
        f4v r1 = {r[4], r[5], r[6], r[7]};
        __builtin_nontemporal_store(r0, (f4v*)orow);
        __builtin_nontemporal_store(r1, (f4v*)(orow + 4));
    }
}

// ---------------- launch ----------------
extern "C" void kernel_launch(void* const* d_in, const int* in_sizes, int n_in,
                              void* d_out, int out_size, void* d_ws, size_t ws_size,
                              hipStream_t stream) {
    const float* x = (const float*)d_in[0];
    const int* ei = (const int*)d_in[1];
    const float* W1 = (const float*)d_in[2];
    const float* b1 = (const float*)d_in[3];
    const float* W2 = (const float*)d_in[4];
    const float* b2 = (const float*)d_in[5];
    float* out = (float*)d_out;

    const int N = in_sizes[0] / NFEAT;  // 100000  (< 2^17 for 4B edge pack)
    const int E = in_sizes[1] / 2;      // 1600000
    const int* src = ei;
    const int* dst = ei + E;
    const int NB = (N + (1 << BSH) - 1) >> BSH;  // 782

    char* w = (char*)d_ws;
    size_t off = 0;
    auto alloc = [&](size_t bytes) -> void* {
        void* p = w + off;
        off = (off + bytes + 511) & ~(size_t)511;
        return p;
    };
    ushort* hs = (ushort*)alloc((size_t)N * NFEAT * 2);
    ushort* y1 = (ushort*)alloc((size_t)N * NFEAT * 2);
    int* row_ptr = (int*)alloc((size_t)(N + 1) * 4);
    float* dinv = (float*)alloc((size_t)N * 4);
    int* col = (int*)alloc((size_t)(E + 64) * 4);   // +64: agg prefetch over-read pad
    uint* ebuf = (uint*)alloc((size_t)NB * BCAP * 4);  // 12.8 MB
    int* gcnt = (int*)alloc((size_t)MAXNB * 4);
    (void)ws_size; (void)n_in; (void)out_size;

    const int CH = 2048;
    const int chBlk = (E + CH - 1) / CH;          // 782 scatter chunks
    const int gemmBlk = (N + 63) / 64;            // 1563 gemm tiles (4 waves x 16 rows)
    const int aggBlk = (N + 15) / 16;             // 16 nodes per block

    hipMemsetAsync(gcnt, 0, (size_t)MAXNB * 4, stream);
    // fused: edge scatter (1/3 of blocks) + layer-1 GEMM (2/3), interleaved
    k_fused1<<<chBlk + gemmBlk, 256, 0, stream>>>(src, dst, gcnt, ebuf, E, NB, CH, chBlk,
                                                  x, W1, hs, N);
    k_fill2<<<NB, 256, 0, stream>>>(ebuf, gcnt, row_ptr, dinv, col, N, E, NB);

    k_aggregate<true><<<aggBlk, 256, 0, stream>>>((const uint4*)hs, row_ptr, col, dinv, b1, y1, N);
    k_gemm3<true><<<gemmBlk, 256, 0, stream>>>(y1, W2, hs, N);
    k_aggregate<false><<<aggBlk, 256, 0, stream>>>((const uint4*)hs, row_ptr, col, dinv, b2, out, N);
}